// Round 6
// baseline (316.593 us; speedup 1.0000x reference)
//
#include <hip/hip_runtime.h>
#include <math.h>

#define B_ 4
#define C_ 128
#define H_ 256
#define W_ 256
#define NPIX (H_*W_)
#define HEADS_ 4

typedef unsigned int uint;
typedef unsigned short ushort;
typedef __attribute__((ext_vector_type(8))) __bf16 bf16x8;
typedef __attribute__((ext_vector_type(4))) float f32x4;

__device__ __forceinline__ ushort f2bf(float f){
    uint u = __builtin_bit_cast(uint, f);
    u += 0x7FFFu + ((u>>16)&1u);        // round-to-nearest-even
    return (ushort)(u>>16);
}
__device__ __forceinline__ float bf2f(ushort h){
    uint u = ((uint)h)<<16;
    return __builtin_bit_cast(float, u);
}
__device__ __forceinline__ __bf16 f2bfv(float f){
    return __builtin_bit_cast(__bf16, f2bf(f));
}
__device__ __forceinline__ int swz3(int i){ return (i ^ (i>>3)) & 7; }

// ---------------------------------------------------------------------------
// K12: fused  S[b] += x^T x  AND  vinp = x @ Wv.
// ---------------------------------------------------------------------------
__global__ __launch_bounds__(512) void k12(const float* __restrict__ x, const float* __restrict__ Wv,
                                           float* __restrict__ S, ushort* __restrict__ vinp){
    __shared__ __align__(16) char smX[32768];
    __shared__ __align__(16) char smT[32768];
    int blk = blockIdx.x;
    int b = blk >> 7, chunk = blk & 127;
    long base = ((long)b*NPIX + (long)chunk*512) * C_;
    int t = threadIdx.x, lane = t & 63, w = t >> 6;
    int wm = w >> 2, wn = w & 3;
    int m0 = wm*64, n0 = wn*32;

    // preload Wv B-fragments: B[k=in][col=out]
    bf16x8 Bv[4][2];
    #pragma unroll
    for(int kk=0;kk<4;kk++){
        int kb = kk*32 + (lane>>4)*8;
        #pragma unroll
        for(int j=0;j<2;j++){
            int col = n0 + j*16 + (lane&15);
            bf16x8 v;
            #pragma unroll
            for(int jj=0;jj<8;jj++) v[jj] = f2bfv(Wv[(kb+jj)*C_ + col]);
            Bv[kk][j] = v;
        }
    }

    f32x4 acc_s[4][2];
    #pragma unroll
    for(int i=0;i<4;i++)
        #pragma unroll
        for(int j=0;j<2;j++) acc_s[i][j] = {0.f,0.f,0.f,0.f};

    for(int tile=0; tile<4; ++tile){
        {
            int rp = (t>>5)*2;
            int c0 = (t&31)*4;
            const float* xp = x + base + (long)tile*128*C_;
            #pragma unroll
            for(int p=0;p<4;p++){
                int r = p*32 + rp;
                float4 a0 = *(const float4*)(xp + r*C_ + c0);
                float4 a1 = *(const float4*)(xp + (r+1)*C_ + c0);
                ushort h0[4] = {f2bf(a0.x), f2bf(a0.y), f2bf(a0.z), f2bf(a0.w)};
                ushort h1[4] = {f2bf(a1.x), f2bf(a1.y), f2bf(a1.z), f2bf(a1.w)};
                uint2 pk0, pk1;
                pk0.x = (uint)h0[0] | ((uint)h0[1]<<16);
                pk0.y = (uint)h0[2] | ((uint)h0[3]<<16);
                pk1.x = (uint)h1[0] | ((uint)h1[1]<<16);
                pk1.y = (uint)h1[2] | ((uint)h1[3]<<16);
                *(uint2*)(smX + r*256     + ((2*c0) ^ (swz3(r)<<4)))   = pk0;
                *(uint2*)(smX + (r+1)*256 + ((2*c0) ^ (swz3(r+1)<<4))) = pk1;
                #pragma unroll
                for(int i=0;i<4;i++){
                    int ch = c0+i;
                    uint pk = (uint)h0[i] | ((uint)h1[i]<<16);
                    *(uint*)(smT + ch*256 + ((2*r) ^ (swz3(ch)<<4))) = pk;
                }
            }
        }
        __syncthreads();

        f32x4 acc_v[4][2];
        #pragma unroll
        for(int i=0;i<4;i++)
            #pragma unroll
            for(int j=0;j<2;j++) acc_v[i][j] = {0.f,0.f,0.f,0.f};

        #pragma unroll
        for(int kk=0;kk<4;kk++){
            int kb = kk*32 + (lane>>4)*8;
            bf16x8 A[4];
            #pragma unroll
            for(int i=0;i<4;i++){
                int r = m0 + i*16 + (lane&15);
                A[i] = *(const bf16x8*)(smX + r*256 + ((2*kb) ^ (swz3(r)<<4)));
            }
            #pragma unroll
            for(int i=0;i<4;i++)
                #pragma unroll
                for(int j=0;j<2;j++)
                    acc_v[i][j] = __builtin_amdgcn_mfma_f32_16x16x32_bf16(A[i], Bv[kk][j], acc_v[i][j], 0,0,0);
            bf16x8 As[4], Bs[2];
            #pragma unroll
            for(int i=0;i<4;i++){
                int ch = m0 + i*16 + (lane&15);
                As[i] = *(const bf16x8*)(smT + ch*256 + ((2*kb) ^ (swz3(ch)<<4)));
            }
            #pragma unroll
            for(int j=0;j<2;j++){
                int ch = n0 + j*16 + (lane&15);
                Bs[j] = *(const bf16x8*)(smT + ch*256 + ((2*kb) ^ (swz3(ch)<<4)));
            }
            #pragma unroll
            for(int i=0;i<4;i++)
                #pragma unroll
                for(int j=0;j<2;j++)
                    acc_s[i][j] = __builtin_amdgcn_mfma_f32_16x16x32_bf16(As[i], Bs[j], acc_s[i][j], 0,0,0);
        }
        __syncthreads();
        {
            int rq = (lane>>4)*4, cc = lane&15;
            #pragma unroll
            for(int i=0;i<4;i++)
                #pragma unroll
                for(int j=0;j<2;j++)
                    #pragma unroll
                    for(int rg=0;rg<4;rg++){
                        int row = m0 + i*16 + rq + rg;
                        int col = n0 + j*16 + cc;
                        *(ushort*)(smX + row*256 + ((2*col) ^ (swz3(row)<<4))) = f2bf(acc_v[i][j][rg]);
                    }
        }
        __syncthreads();
        {
            long off = base + (long)tile*128*C_;
            #pragma unroll
            for(int p=0;p<4;p++){
                int idx = p*512 + t;
                int row = idx >> 4, ub = idx & 15;
                uint4 d = *(const uint4*)(smX + row*256 + ((ub*16) ^ (swz3(row)<<4)));
                *(uint4*)(vinp + off + row*C_ + ub*8) = d;
            }
        }
        __syncthreads();
    }
    float* Sb = S + b*C_*C_;
    int rq = (lane>>4)*4, cc = lane&15;
    #pragma unroll
    for(int i=0;i<4;i++)
        #pragma unroll
        for(int j=0;j<2;j++)
            #pragma unroll
            for(int rg=0;rg<4;rg++){
                int row = m0 + i*16 + rq + rg;
                int col = n0 + j*16 + cc;
                atomicAdd(&Sb[row*C_ + col], acc_s[i][j][rg]);
            }
}

// ---------------------------------------------------------------------------
// K3a: TQ = S@Wq (stored), U = S@Wk (norm contributions only).
// ---------------------------------------------------------------------------
__global__ __launch_bounds__(256) void k3a(const float* __restrict__ S, const float* __restrict__ Wq,
                                           const float* __restrict__ Wk, float* __restrict__ TQ,
                                           float* __restrict__ nrm){
    int b = blockIdx.x >> 7, c = blockIdx.x & 127;
    __shared__ float sS[C_];
    int t = threadIdx.x;
    if(t < C_) sS[t] = S[(b*C_+c)*C_ + t];
    __syncthreads();
    const float* Wm = (t < C_) ? Wq : Wk;
    int col = t & (C_-1);
    float acc = 0.f;
    #pragma unroll 4
    for(int c2=0;c2<C_;c2++) acc += sS[c2] * Wm[c2*C_ + col];
    if(t < C_){
        TQ[(b*C_+c)*C_ + col] = acc;
        atomicAdd(&nrm[b*256 + col], Wq[c*C_+col]*acc);
    } else {
        atomicAdd(&nrm[b*256 + C_ + col], Wk[c*C_+col]*acc);
    }
}

// ---------------------------------------------------------------------------
// K3b: per (b,h): G = Wk_h^T TQ_h, scaled softmax, WeffT = attn @ Wp_h.
// ---------------------------------------------------------------------------
__global__ __launch_bounds__(256) void k3b(const float* __restrict__ TQ, const float* __restrict__ Wk,
                                           const float* __restrict__ rescale, const float* __restrict__ Wp,
                                           const float* __restrict__ nrm, ushort* __restrict__ WeffT){
    int b = blockIdx.x >> 2, h = blockIdx.x & 3;
    int t = threadIdx.x;
    __shared__ float sTQ[C_*32];
    __shared__ float sWk[C_*32];
    __shared__ float sG[32*32];
    __shared__ float sinq[32], sink[32];

    #pragma unroll
    for(int p=0;p<16;p++){
        int idx = p*256 + t;
        int c = idx >> 5, e = idx & 31;
        sTQ[idx] = TQ[(b*C_+c)*C_ + h*32 + e];
        sWk[idx] = Wk[c*C_ + h*32 + e];
    }
    if(t < 32) sinq[t] = 1.f/fmaxf(sqrtf(fmaxf(nrm[b*256 + h*32 + t], 0.f)), 1e-12f);
    else if(t < 64) sink[t-32] = 1.f/fmaxf(sqrtf(fmaxf(nrm[b*256 + C_ + h*32 + (t-32)], 0.f)), 1e-12f);
    __syncthreads();

    float g[4];
    #pragma unroll
    for(int p=0;p<4;p++){
        int idx = p*256 + t;
        int d = idx >> 5, e = idx & 31;
        float a = 0.f;
        #pragma unroll 4
        for(int c=0;c<C_;c++) a += sWk[c*32+d]*sTQ[c*32+e];
        g[p] = a;
    }
    #pragma unroll
    for(int p=0;p<4;p++) sG[p*256 + t] = g[p];
    __syncthreads();

    if(t < 32){
        int d = t;
        float rs = rescale[h] * sink[d];
        float l[32]; float mx = -1e30f;
        #pragma unroll
        for(int e=0;e<32;e++){ l[e] = sG[d*32+e]*rs*sinq[e]; mx = fmaxf(mx, l[e]); }
        float sum = 0.f;
        #pragma unroll
        for(int e=0;e<32;e++){ l[e] = expf(l[e]-mx); sum += l[e]; }
        float inv = 1.f/sum;
        #pragma unroll
        for(int e=0;e<32;e++) sG[d*32+e] = l[e]*inv;
    }
    __syncthreads();

    #pragma unroll
    for(int p=0;p<16;p++){
        int idx = p*256 + t;
        int d = idx >> 7, c = idx & 127;
        sTQ[idx] = Wp[(h*32+d)*C_ + c];
    }
    __syncthreads();

    #pragma unroll
    for(int p=0;p<16;p++){
        int idx = p*256 + t;
        int c = idx >> 5, e = idx & 31;
        float a = 0.f;
        #pragma unroll
        for(int d=0;d<32;d++) a += sG[d*32+e]*sTQ[d*128+c];
        WeffT[((long)b*C_+c)*C_ + h*32 + e] = f2bf(a);
    }
}

// ---------------------------------------------------------------------------
// K4a: c1 = gelu(dwconv3x3(v_inp, w1)) — sliding window + XCD swizzle.
// ---------------------------------------------------------------------------
__global__ __launch_bounds__(256) void k4a_conv1(const ushort* __restrict__ vinp, const float* __restrict__ w1,
                                                 ushort* __restrict__ c1){
    int blk0 = blockIdx.x;
    int blk = (blk0 & 7)*128 + (blk0 >> 3);   // bijective XCD swizzle (1024 % 8 == 0)
    int b = blk >> 8; int y = blk & 255;
    int t = threadIdx.x;
    int c0 = (t & 15)*8;
    int pg = t >> 4;
    float wreg[9][8];
    #pragma unroll
    for(int k=0;k<9;k++){
        float4 a = *(const float4*)(w1 + k*C_ + c0);
        float4 bq = *(const float4*)(w1 + k*C_ + c0 + 4);
        wreg[k][0]=a.x; wreg[k][1]=a.y; wreg[k][2]=a.z; wreg[k][3]=a.w;
        wreg[k][4]=bq.x; wreg[k][5]=bq.y; wreg[k][6]=bq.z; wreg[k][7]=bq.w;
    }
    const ushort* vb = vinp + (long)b*NPIX*C_;
    ushort* cb = c1 + (long)b*NPIX*C_;

    float colA[3][8], colB[3][8], colC[3][8];
    int xbase = pg*16;

    auto loadcol = [&](float (*col)[8], int xcol){
        #pragma unroll
        for(int ky=0;ky<3;ky++){
            int yy = y + ky - 1;
            if(xcol>=0 && xcol<W_ && yy>=0 && yy<H_){
                uint4 vv = *(const uint4*)(vb + ((long)yy*W_ + xcol)*C_ + c0);
                const ushort* pv = (const ushort*)&vv;
                #pragma unroll
                for(int i=0;i<8;i++) col[ky][i] = bf2f(pv[i]);
            } else {
                #pragma unroll
                for(int i=0;i<8;i++) col[ky][i] = 0.f;
            }
        }
    };
    loadcol(colA, xbase-1);
    loadcol(colB, xbase);
    #pragma unroll
    for(int q=0;q<16;q++){
        int xx = xbase + q;
        loadcol(colC, xx+1);
        float s[8];
        #pragma unroll
        for(int i=0;i<8;i++){
            float a = 0.f;
            #pragma unroll
            for(int ky=0;ky<3;ky++){
                a += colA[ky][i]*wreg[ky*3+0][i];
                a += colB[ky][i]*wreg[ky*3+1][i];
                a += colC[ky][i]*wreg[ky*3+2][i];
            }
            s[i] = a;
        }
        uint op[4];
        #pragma unroll
        for(int i2=0;i2<4;i2++){
            float va = s[i2*2],   ga = 0.5f*va*(1.0f+erff(va*0.70710678118654752f));
            float vb2 = s[i2*2+1], gb = 0.5f*vb2*(1.0f+erff(vb2*0.70710678118654752f));
            op[i2] = (uint)f2bf(ga) | ((uint)f2bf(gb)<<16);
        }
        uint4 o; o.x=op[0]; o.y=op[1]; o.z=op[2]; o.w=op[3];
        *(uint4*)(cb + ((long)y*W_ + xx)*C_ + c0) = o;
        #pragma unroll
        for(int ky=0;ky<3;ky++)
            #pragma unroll
            for(int i=0;i<8;i++){ colA[ky][i]=colB[ky][i]; colB[ky][i]=colC[ky][i]; }
    }
}

// ---------------------------------------------------------------------------
// K4bc v4: 32 KB LDS total (4 blocks/CU). GEMM (Weff B-frags in regs) ->
// f32 bounce + conv2 in TWO 64-row halves over the SAME 32 KB (aliased).
// ---------------------------------------------------------------------------
__global__ __launch_bounds__(512) void k4bc(const ushort* __restrict__ vinp, const float* __restrict__ ilf,
                                            const ushort* __restrict__ WeffT, const float* __restrict__ bp,
                                            const ushort* __restrict__ c1, const float* __restrict__ w2,
                                            float* __restrict__ out){
    __shared__ __align__(16) char smem[32768];
    char* smv = smem;            // 32 KB: gated v tile bf16 [128px][128ch] (phase 1)
    char* smo = smem;            // 32 KB: f32 half-tile [64px][128col], 512B rows (phases 2/3)

    int blk0 = blockIdx.x;
    int blk = (blk0 & 7)*256 + (blk0 >> 3);   // bijective XCD swizzle (2048 % 8 == 0)
    int b = blk >> 9; int tileI = blk & 511;
    long rowbase = (long)b*NPIX + (long)tileI*128;
    int t = threadIdx.x, lane = t&63, w = t>>6;
    int wm = w>>2, wn = w&3;
    int m0 = wm*64, n0 = wn*32;

    // preload Weff B-frags (WeffT[b] is [c][he] row-major; B[k=c][col=he])
    bf16x8 Bw[4][2];
    {
        const ushort* wp = WeffT + b*C_*C_;
        #pragma unroll
        for(int kk=0;kk<4;kk++){
            int kb = kk*32 + (lane>>4)*8;
            #pragma unroll
            for(int j=0;j<2;j++){
                int col = n0 + j*16 + (lane&15);
                Bw[kk][j] = *(const bf16x8*)(wp + col*C_ + kb);
            }
        }
    }
    // stage vg = vinp .* ilf
    {
        const ushort* vp = vinp + rowbase*C_;
        const float*  ip = ilf + rowbase*C_;
        #pragma unroll
        for(int p=0;p<4;p++){
            int idx = p*512 + t;
            int r = idx >> 4;
            int cl = (idx & 15)*8;
            uint4 vv = *(const uint4*)(vp + r*C_ + cl);
            const ushort* pv = (const ushort*)&vv;
            float4 i0 = *(const float4*)(ip + r*C_ + cl);
            float4 i1 = *(const float4*)(ip + r*C_ + cl + 4);
            uint4 pk;
            pk.x = (uint)f2bf(bf2f(pv[0])*i0.x) | ((uint)f2bf(bf2f(pv[1])*i0.y)<<16);
            pk.y = (uint)f2bf(bf2f(pv[2])*i0.z) | ((uint)f2bf(bf2f(pv[3])*i0.w)<<16);
            pk.z = (uint)f2bf(bf2f(pv[4])*i1.x) | ((uint)f2bf(bf2f(pv[5])*i1.y)<<16);
            pk.w = (uint)f2bf(bf2f(pv[6])*i1.z) | ((uint)f2bf(bf2f(pv[7])*i1.w)<<16);
            *(uint4*)(smv + r*256 + ((2*cl) ^ (swz3(r)<<4))) = pk;
        }
    }
    __syncthreads();

    f32x4 acc[4][2];
    #pragma unroll
    for(int i=0;i<4;i++)
        #pragma unroll
        for(int j=0;j<2;j++) acc[i][j] = {0.f,0.f,0.f,0.f};

    #pragma unroll
    for(int kk=0;kk<4;kk++){
        int kb = kk*32 + (lane>>4)*8;
        bf16x8 A[4];
        #pragma unroll
        for(int i=0;i<4;i++){
            int r = m0 + i*16 + (lane&15);
            A[i] = *(const bf16x8*)(smv + r*256 + ((2*kb) ^ (swz3(r)<<4)));
        }
        #pragma unroll
        for(int i=0;i<4;i++)
            #pragma unroll
            for(int j=0;j<2;j++)
                acc[i][j] = __builtin_amdgcn_mfma_f32_16x16x32_bf16(A[i], Bw[kk][j], acc[i][j], 0,0,0);
    }
    __syncthreads();     // all smv reads done; smem becomes smo (f32 half)

    // conv setup (shared by both halves)
    int yt = tileI >> 1;
    int x0 = (tileI & 1) << 7;
    int c0 = (t & 15)*8;
    int pg = t >> 4;               // 32 groups x 2 px per half
    float wreg[9][8];
    #pragma unroll
    for(int k=0;k<9;k++){
        float4 a = *(const float4*)(w2 + k*C_ + c0);
        float4 bq = *(const float4*)(w2 + k*C_ + c0 + 4);
        wreg[k][0]=a.x; wreg[k][1]=a.y; wreg[k][2]=a.z; wreg[k][3]=a.w;
        wreg[k][4]=bq.x; wreg[k][5]=bq.y; wreg[k][6]=bq.z; wreg[k][7]=bq.w;
    }
    float bias[8];
    {
        float4 b0 = *(const float4*)(bp + c0);
        float4 b1 = *(const float4*)(bp + c0 + 4);
        bias[0]=b0.x; bias[1]=b0.y; bias[2]=b0.z; bias[3]=b0.w;
        bias[4]=b1.x; bias[5]=b1.y; bias[6]=b1.z; bias[7]=b1.w;
    }
    const ushort* cb = c1 + (long)b*NPIX*C_;
    float* ob = out + ((long)b*NPIX + (long)yt*W_)*C_;

    #pragma unroll
    for(int hh=0; hh<2; ++hh){
        // bounce: waves owning rows [hh*64, hh*64+64) write their acc
        if(wm == hh){
            int rq = (lane>>4)*4, cc = lane&15;
            #pragma unroll
            for(int i=0;i<4;i++)
                #pragma unroll
                for(int j=0;j<2;j++)
                    #pragma unroll
                    for(int rg=0;rg<4;rg++){
                        int rrel = i*16 + rq + rg;           // 0..63
                        int col = n0 + j*16 + cc;
                        *(float*)(smo + rrel*512 + ((col*4) ^ (swz3(rrel)<<4))) = acc[i][j][rg];
                    }
        }
        __syncthreads();

        // conv2 for this half's 64 px: all 512 threads, 2 px each
        float colA[3][8], colB[3][8], colC[3][8];
        int xrel0 = hh*64 + pg*2;
        int xbase = x0 + xrel0;

        auto loadcol = [&](float (*col)[8], int xcol){
            #pragma unroll
            for(int ky=0;ky<3;ky++){
                int yy = yt + ky - 1;
                if(xcol>=0 && xcol<W_ && yy>=0 && yy<H_){
                    uint4 vv = *(const uint4*)(cb + ((long)yy*W_ + xcol)*C_ + c0);
                    const ushort* pv = (const ushort*)&vv;
                    #pragma unroll
                    for(int i=0;i<8;i++) col[ky][i] = bf2f(pv[i]);
                } else {
                    #pragma unroll
                    for(int i=0;i<8;i++) col[ky][i] = 0.f;
                }
            }
        };
        loadcol(colA, xbase-1);
        loadcol(colB, xbase);
        #pragma unroll
        for(int q=0;q<2;q++){
            int xx = xbase + q;
            int rrel = pg*2 + q;          // 0..63 within half
            loadcol(colC, xx+1);
            float s[8];
            #pragma unroll
            for(int i=0;i<8;i++){
                float a = 0.f;
                #pragma unroll
                for(int ky=0;ky<3;ky++){
                    a += colA[ky][i]*wreg[ky*3+0][i];
                    a += colB[ky][i]*wreg[ky*3+1][i];
                    a += colC[ky][i]*wreg[ky*3+2][i];
                }
                s[i] = a;
            }
            float4 m0v = *(const float4*)(smo + rrel*512 + (((c0  )*4) ^ (swz3(rrel)<<4)));
            float4 m1v = *(const float4*)(smo + rrel*512 + (((c0+4)*4) ^ (swz3(rrel)<<4)));
            float4 o0, o1;
            o0.x = m0v.x + bias[0] + s[0];
            o0.y = m0v.y + bias[1] + s[1];
            o0.z = m0v.z + bias[2] + s[2];
            o0.w = m0v.w + bias[3] + s[3];
            o1.x = m1v.x + bias[4] + s[4];
            o1.y = m1v.y + bias[5] + s[5];
            o1.z = m1v.z + bias[6] + s[6];
            o1.w = m1v.w + bias[7] + s[7];
            float* op2 = ob + (long)xx*C_ + c0;
            *(float4*)(op2)     = o0;
            *(float4*)(op2 + 4) = o1;
            #pragma unroll
            for(int ky=0;ky<3;ky++)
                #pragma unroll
                for(int i=0;i<8;i++){ colA[ky][i]=colB[ky][i]; colB[ky][i]=colC[ky][i]; }
        }
        if(hh == 0) __syncthreads();   // conv half-0 reads done before half-1 bounce
    }
}

extern "C" void kernel_launch(void* const* d_in, const int* in_sizes, int n_in,
                              void* d_out, int out_size, void* d_ws, size_t ws_size,
                              hipStream_t stream){
    (void)in_sizes; (void)n_in; (void)out_size; (void)ws_size;
    const float* x    = (const float*)d_in[0];
    const float* ilf  = (const float*)d_in[1];
    const float* Wq   = (const float*)d_in[2];
    const float* Wk   = (const float*)d_in[3];
    const float* Wv   = (const float*)d_in[4];
    const float* rsc  = (const float*)d_in[5];
    const float* Wp   = (const float*)d_in[6];
    const float* bp   = (const float*)d_in[7];
    const float* w1   = (const float*)d_in[8];
    const float* w2   = (const float*)d_in[9];
    float* out = (float*)d_out;
    char* ws = (char*)d_ws;

    ushort* vinp  = (ushort*)ws;                       // 64 MiB
    ushort* c1    = (ushort*)(ws + 67108864);          // 64 MiB (written by k4a)
    float*  TQ    = (float*)(ws + 67108864);           // 256 KiB, aliases c1 (dead until k4a)
    float*  S     = (float*)(ws + 134217728);          // 256 KiB  [zeroed]
    float*  nrm   = (float*)(ws + 134479872);          // 4 KiB    [zeroed]
    ushort* WeffT = (ushort*)(ws + 134483968);         // 128 KiB

    hipMemsetAsync(S, 0, 262144 + 4096, stream);
    hipLaunchKernelGGL(k12,      dim3(512),  dim3(512), 0, stream, x, Wv, S, vinp);
    hipLaunchKernelGGL(k3a,      dim3(512),  dim3(256), 0, stream, S, Wq, Wk, TQ, nrm);
    hipLaunchKernelGGL(k3b,      dim3(16),   dim3(256), 0, stream, TQ, Wk, rsc, Wp, nrm, WeffT);
    hipLaunchKernelGGL(k4a_conv1,dim3(1024), dim3(256), 0, stream, vinp, w1, c1);
    hipLaunchKernelGGL(k4bc,     dim3(2048), dim3(512), 0, stream, vinp, ilf, WeffT, bp, c1, w2, out);
}

// Round 7
// 279.669 us; speedup vs baseline: 1.1320x; 1.1320x over previous
//
#include <hip/hip_runtime.h>
#include <math.h>

#define B_ 4
#define C_ 128
#define H_ 256
#define W_ 256
#define NPIX (H_*W_)
#define HEADS_ 4

typedef unsigned int uint;
typedef unsigned short ushort;
typedef __attribute__((ext_vector_type(8))) __bf16 bf16x8;
typedef __attribute__((ext_vector_type(4))) float f32x4;

__device__ __forceinline__ ushort f2bf(float f){
    uint u = __builtin_bit_cast(uint, f);
    u += 0x7FFFu + ((u>>16)&1u);        // round-to-nearest-even
    return (ushort)(u>>16);
}
__device__ __forceinline__ float bf2f(ushort h){
    uint u = ((uint)h)<<16;
    return __builtin_bit_cast(float, u);
}
__device__ __forceinline__ __bf16 f2bfv(float f){
    return __builtin_bit_cast(__bf16, f2bf(f));
}
__device__ __forceinline__ int swz3(int i){ return (i ^ (i>>3)) & 7; }

// ---------------------------------------------------------------------------
// K12: fused  S[b] += x^T x  AND  vinp = x @ Wv.
// ---------------------------------------------------------------------------
__global__ __launch_bounds__(512) void k12(const float* __restrict__ x, const float* __restrict__ Wv,
                                           float* __restrict__ S, ushort* __restrict__ vinp){
    __shared__ __align__(16) char smX[32768];
    __shared__ __align__(16) char smT[32768];
    int blk = blockIdx.x;
    int b = blk >> 7, chunk = blk & 127;
    long base = ((long)b*NPIX + (long)chunk*512) * C_;
    int t = threadIdx.x, lane = t & 63, w = t >> 6;
    int wm = w >> 2, wn = w & 3;
    int m0 = wm*64, n0 = wn*32;

    // preload Wv B-fragments: B[k=in][col=out]
    bf16x8 Bv[4][2];
    #pragma unroll
    for(int kk=0;kk<4;kk++){
        int kb = kk*32 + (lane>>4)*8;
        #pragma unroll
        for(int j=0;j<2;j++){
            int col = n0 + j*16 + (lane&15);
            bf16x8 v;
            #pragma unroll
            for(int jj=0;jj<8;jj++) v[jj] = f2bfv(Wv[(kb+jj)*C_ + col]);
            Bv[kk][j] = v;
        }
    }

    f32x4 acc_s[4][2];
    #pragma unroll
    for(int i=0;i<4;i++)
        #pragma unroll
        for(int j=0;j<2;j++) acc_s[i][j] = {0.f,0.f,0.f,0.f};

    for(int tile=0; tile<4; ++tile){
        {
            int rp = (t>>5)*2;
            int c0 = (t&31)*4;
            const float* xp = x + base + (long)tile*128*C_;
            #pragma unroll
            for(int p=0;p<4;p++){
                int r = p*32 + rp;
                float4 a0 = *(const float4*)(xp + r*C_ + c0);
                float4 a1 = *(const float4*)(xp + (r+1)*C_ + c0);
                ushort h0[4] = {f2bf(a0.x), f2bf(a0.y), f2bf(a0.z), f2bf(a0.w)};
                ushort h1[4] = {f2bf(a1.x), f2bf(a1.y), f2bf(a1.z), f2bf(a1.w)};
                uint2 pk0, pk1;
                pk0.x = (uint)h0[0] | ((uint)h0[1]<<16);
                pk0.y = (uint)h0[2] | ((uint)h0[3]<<16);
                pk1.x = (uint)h1[0] | ((uint)h1[1]<<16);
                pk1.y = (uint)h1[2] | ((uint)h1[3]<<16);
                *(uint2*)(smX + r*256     + ((2*c0) ^ (swz3(r)<<4)))   = pk0;
                *(uint2*)(smX + (r+1)*256 + ((2*c0) ^ (swz3(r+1)<<4))) = pk1;
                #pragma unroll
                for(int i=0;i<4;i++){
                    int ch = c0+i;
                    uint pk = (uint)h0[i] | ((uint)h1[i]<<16);
                    *(uint*)(smT + ch*256 + ((2*r) ^ (swz3(ch)<<4))) = pk;
                }
            }
        }
        __syncthreads();

        f32x4 acc_v[4][2];
        #pragma unroll
        for(int i=0;i<4;i++)
            #pragma unroll
            for(int j=0;j<2;j++) acc_v[i][j] = {0.f,0.f,0.f,0.f};

        #pragma unroll
        for(int kk=0;kk<4;kk++){
            int kb = kk*32 + (lane>>4)*8;
            bf16x8 A[4];
            #pragma unroll
            for(int i=0;i<4;i++){
                int r = m0 + i*16 + (lane&15);
                A[i] = *(const bf16x8*)(smX + r*256 + ((2*kb) ^ (swz3(r)<<4)));
            }
            #pragma unroll
            for(int i=0;i<4;i++)
                #pragma unroll
                for(int j=0;j<2;j++)
                    acc_v[i][j] = __builtin_amdgcn_mfma_f32_16x16x32_bf16(A[i], Bv[kk][j], acc_v[i][j], 0,0,0);
            bf16x8 As[4], Bs[2];
            #pragma unroll
            for(int i=0;i<4;i++){
                int ch = m0 + i*16 + (lane&15);
                As[i] = *(const bf16x8*)(smT + ch*256 + ((2*kb) ^ (swz3(ch)<<4)));
            }
            #pragma unroll
            for(int j=0;j<2;j++){
                int ch = n0 + j*16 + (lane&15);
                Bs[j] = *(const bf16x8*)(smT + ch*256 + ((2*kb) ^ (swz3(ch)<<4)));
            }
            #pragma unroll
            for(int i=0;i<4;i++)
                #pragma unroll
                for(int j=0;j<2;j++)
                    acc_s[i][j] = __builtin_amdgcn_mfma_f32_16x16x32_bf16(As[i], Bs[j], acc_s[i][j], 0,0,0);
        }
        __syncthreads();
        {
            int rq = (lane>>4)*4, cc = lane&15;
            #pragma unroll
            for(int i=0;i<4;i++)
                #pragma unroll
                for(int j=0;j<2;j++)
                    #pragma unroll
                    for(int rg=0;rg<4;rg++){
                        int row = m0 + i*16 + rq + rg;
                        int col = n0 + j*16 + cc;
                        *(ushort*)(smX + row*256 + ((2*col) ^ (swz3(row)<<4))) = f2bf(acc_v[i][j][rg]);
                    }
        }
        __syncthreads();
        {
            long off = base + (long)tile*128*C_;
            #pragma unroll
            for(int p=0;p<4;p++){
                int idx = p*512 + t;
                int row = idx >> 4, ub = idx & 15;
                uint4 d = *(const uint4*)(smX + row*256 + ((ub*16) ^ (swz3(row)<<4)));
                *(uint4*)(vinp + off + row*C_ + ub*8) = d;
            }
        }
        __syncthreads();
    }
    float* Sb = S + b*C_*C_;
    int rq = (lane>>4)*4, cc = lane&15;
    #pragma unroll
    for(int i=0;i<4;i++)
        #pragma unroll
        for(int j=0;j<2;j++)
            #pragma unroll
            for(int rg=0;rg<4;rg++){
                int row = m0 + i*16 + rq + rg;
                int col = n0 + j*16 + cc;
                atomicAdd(&Sb[row*C_ + col], acc_s[i][j][rg]);
            }
}

// ---------------------------------------------------------------------------
// K3a: TQ = S@Wq (stored), U = S@Wk (norm contributions only).
// ---------------------------------------------------------------------------
__global__ __launch_bounds__(256) void k3a(const float* __restrict__ S, const float* __restrict__ Wq,
                                           const float* __restrict__ Wk, float* __restrict__ TQ,
                                           float* __restrict__ nrm){
    int b = blockIdx.x >> 7, c = blockIdx.x & 127;
    __shared__ float sS[C_];
    int t = threadIdx.x;
    if(t < C_) sS[t] = S[(b*C_+c)*C_ + t];
    __syncthreads();
    const float* Wm = (t < C_) ? Wq : Wk;
    int col = t & (C_-1);
    float acc = 0.f;
    #pragma unroll 4
    for(int c2=0;c2<C_;c2++) acc += sS[c2] * Wm[c2*C_ + col];
    if(t < C_){
        TQ[(b*C_+c)*C_ + col] = acc;
        atomicAdd(&nrm[b*256 + col], Wq[c*C_+col]*acc);
    } else {
        atomicAdd(&nrm[b*256 + C_ + col], Wk[c*C_+col]*acc);
    }
}

// ---------------------------------------------------------------------------
// K3b: per (b,h): G = Wk_h^T TQ_h, scaled softmax, WeffT = attn @ Wp_h.
// ---------------------------------------------------------------------------
__global__ __launch_bounds__(256) void k3b(const float* __restrict__ TQ, const float* __restrict__ Wk,
                                           const float* __restrict__ rescale, const float* __restrict__ Wp,
                                           const float* __restrict__ nrm, ushort* __restrict__ WeffT){
    int b = blockIdx.x >> 2, h = blockIdx.x & 3;
    int t = threadIdx.x;
    __shared__ float sTQ[C_*32];
    __shared__ float sWk[C_*32];
    __shared__ float sG[32*32];
    __shared__ float sinq[32], sink[32];

    #pragma unroll
    for(int p=0;p<16;p++){
        int idx = p*256 + t;
        int c = idx >> 5, e = idx & 31;
        sTQ[idx] = TQ[(b*C_+c)*C_ + h*32 + e];
        sWk[idx] = Wk[c*C_ + h*32 + e];
    }
    if(t < 32) sinq[t] = 1.f/fmaxf(sqrtf(fmaxf(nrm[b*256 + h*32 + t], 0.f)), 1e-12f);
    else if(t < 64) sink[t-32] = 1.f/fmaxf(sqrtf(fmaxf(nrm[b*256 + C_ + h*32 + (t-32)], 0.f)), 1e-12f);
    __syncthreads();

    float g[4];
    #pragma unroll
    for(int p=0;p<4;p++){
        int idx = p*256 + t;
        int d = idx >> 5, e = idx & 31;
        float a = 0.f;
        #pragma unroll 4
        for(int c=0;c<C_;c++) a += sWk[c*32+d]*sTQ[c*32+e];
        g[p] = a;
    }
    #pragma unroll
    for(int p=0;p<4;p++) sG[p*256 + t] = g[p];
    __syncthreads();

    if(t < 32){
        int d = t;
        float rs = rescale[h] * sink[d];
        float l[32]; float mx = -1e30f;
        #pragma unroll
        for(int e=0;e<32;e++){ l[e] = sG[d*32+e]*rs*sinq[e]; mx = fmaxf(mx, l[e]); }
        float sum = 0.f;
        #pragma unroll
        for(int e=0;e<32;e++){ l[e] = expf(l[e]-mx); sum += l[e]; }
        float inv = 1.f/sum;
        #pragma unroll
        for(int e=0;e<32;e++) sG[d*32+e] = l[e]*inv;
    }
    __syncthreads();

    #pragma unroll
    for(int p=0;p<16;p++){
        int idx = p*256 + t;
        int d = idx >> 7, c = idx & 127;
        sTQ[idx] = Wp[(h*32+d)*C_ + c];
    }
    __syncthreads();

    #pragma unroll
    for(int p=0;p<16;p++){
        int idx = p*256 + t;
        int c = idx >> 5, e = idx & 31;
        float a = 0.f;
        #pragma unroll
        for(int d=0;d<32;d++) a += sG[d*32+e]*sTQ[d*128+c];
        WeffT[((long)b*C_+c)*C_ + h*32 + e] = f2bf(a);
    }
}

// ---------------------------------------------------------------------------
// K4a v2: c1 = gelu(dwconv3x3(v_inp, w1)) — 2048 blocks (half-row each),
// 8 px/thread sliding window, XCD swizzle.
// ---------------------------------------------------------------------------
__global__ __launch_bounds__(256) void k4a_conv1(const ushort* __restrict__ vinp, const float* __restrict__ w1,
                                                 ushort* __restrict__ c1){
    int blk0 = blockIdx.x;
    int blk = (blk0 & 7)*256 + (blk0 >> 3);   // bijective XCD swizzle (2048 % 8 == 0)
    int b = blk >> 9; int y = (blk >> 1) & 255; int xh = blk & 1;
    int t = threadIdx.x;
    int c0 = (t & 15)*8;
    int pg = t >> 4;                          // 16 groups x 8 px = 128 px
    float wreg[9][8];
    #pragma unroll
    for(int k=0;k<9;k++){
        float4 a = *(const float4*)(w1 + k*C_ + c0);
        float4 bq = *(const float4*)(w1 + k*C_ + c0 + 4);
        wreg[k][0]=a.x; wreg[k][1]=a.y; wreg[k][2]=a.z; wreg[k][3]=a.w;
        wreg[k][4]=bq.x; wreg[k][5]=bq.y; wreg[k][6]=bq.z; wreg[k][7]=bq.w;
    }
    const ushort* vb = vinp + (long)b*NPIX*C_;
    ushort* cb = c1 + (long)b*NPIX*C_;

    float colA[3][8], colB[3][8], colC[3][8];
    int xbase = xh*128 + pg*8;

    auto loadcol = [&](float (*col)[8], int xcol){
        #pragma unroll
        for(int ky=0;ky<3;ky++){
            int yy = y + ky - 1;
            if(xcol>=0 && xcol<W_ && yy>=0 && yy<H_){
                uint4 vv = *(const uint4*)(vb + ((long)yy*W_ + xcol)*C_ + c0);
                const ushort* pv = (const ushort*)&vv;
                #pragma unroll
                for(int i=0;i<8;i++) col[ky][i] = bf2f(pv[i]);
            } else {
                #pragma unroll
                for(int i=0;i<8;i++) col[ky][i] = 0.f;
            }
        }
    };
    loadcol(colA, xbase-1);
    loadcol(colB, xbase);
    #pragma unroll
    for(int q=0;q<8;q++){
        int xx = xbase + q;
        loadcol(colC, xx+1);
        float s[8];
        #pragma unroll
        for(int i=0;i<8;i++){
            float a = 0.f;
            #pragma unroll
            for(int ky=0;ky<3;ky++){
                a += colA[ky][i]*wreg[ky*3+0][i];
                a += colB[ky][i]*wreg[ky*3+1][i];
                a += colC[ky][i]*wreg[ky*3+2][i];
            }
            s[i] = a;
        }
        uint op[4];
        #pragma unroll
        for(int i2=0;i2<4;i2++){
            float va = s[i2*2],   ga = 0.5f*va*(1.0f+erff(va*0.70710678118654752f));
            float vb2 = s[i2*2+1], gb = 0.5f*vb2*(1.0f+erff(vb2*0.70710678118654752f));
            op[i2] = (uint)f2bf(ga) | ((uint)f2bf(gb)<<16);
        }
        uint4 o; o.x=op[0]; o.y=op[1]; o.z=op[2]; o.w=op[3];
        *(uint4*)(cb + ((long)y*W_ + xx)*C_ + c0) = o;
        #pragma unroll
        for(int ky=0;ky<3;ky++)
            #pragma unroll
            for(int i=0;i<8;i++){ colA[ky][i]=colB[ky][i]; colB[ky][i]=colC[ky][i]; }
    }
}

// ---------------------------------------------------------------------------
// K4bc (R4 structure, best measured): x1 GEMM -> LDS bounce -> + conv2(c1)
// + bias -> SINGLE out store. 256 threads, 64 KB LDS.
// ---------------------------------------------------------------------------
__global__ __launch_bounds__(256) void k4bc(const ushort* __restrict__ vinp, const float* __restrict__ ilf,
                                            const ushort* __restrict__ WeffT, const float* __restrict__ bp,
                                            const ushort* __restrict__ c1, const float* __restrict__ w2,
                                            float* __restrict__ out){
    __shared__ __align__(16) char smem[65536];
    char* smv = smem;            // 32 KB: v tile (phase 1)
    char* smw = smem + 32768;    // 32 KB: Weff  (phase 1)
    float* smo = (float*)smem;   // 64 KB: f32 x1 tile [128px][128ch] (phase 2+)

    int blk0 = blockIdx.x;
    int blk = (blk0 & 7)*256 + (blk0 >> 3);   // bijective XCD swizzle (2048 % 8 == 0)
    int b = blk >> 9; int tileI = blk & 511;
    long rowbase = (long)b*NPIX + (long)tileI*128;
    int t = threadIdx.x, lane=t&63, w=t>>6;
    int m0=(w>>1)*64, n0=(w&1)*64;
    {
        const ushort* wp = WeffT + b*C_*C_;
        #pragma unroll
        for(int p=0;p<8;p++){
            int idx = p*256 + t;
            int cR = idx >> 4; int ub = idx & 15;
            uint4 d = *(const uint4*)(wp + cR*C_ + ub*8);
            *(uint4*)(smw + cR*256 + ((ub*16) ^ (swz3(cR)<<4))) = d;
        }
    }
    {
        const ushort* vp = vinp + rowbase*C_;
        const float*  ip = ilf + rowbase*C_;
        #pragma unroll
        for(int p=0;p<8;p++){
            int r = p*16 + (t>>4);
            int cl = (t&15)*8;
            uint4 vv = *(const uint4*)(vp + r*C_ + cl);
            const ushort* pv = (const ushort*)&vv;
            float4 i0 = *(const float4*)(ip + r*C_ + cl);
            float4 i1 = *(const float4*)(ip + r*C_ + cl + 4);
            uint4 pk;
            pk.x = (uint)f2bf(bf2f(pv[0])*i0.x) | ((uint)f2bf(bf2f(pv[1])*i0.y)<<16);
            pk.y = (uint)f2bf(bf2f(pv[2])*i0.z) | ((uint)f2bf(bf2f(pv[3])*i0.w)<<16);
            pk.z = (uint)f2bf(bf2f(pv[4])*i1.x) | ((uint)f2bf(bf2f(pv[5])*i1.y)<<16);
            pk.w = (uint)f2bf(bf2f(pv[6])*i1.z) | ((uint)f2bf(bf2f(pv[7])*i1.w)<<16);
            *(uint4*)(smv + r*256 + ((2*cl) ^ (swz3(r)<<4))) = pk;
        }
    }
    __syncthreads();

    f32x4 acc[4][4];
    #pragma unroll
    for(int i=0;i<4;i++)
        #pragma unroll
        for(int j=0;j<4;j++) acc[i][j] = {0.f,0.f,0.f,0.f};

    #pragma unroll
    for(int kk=0;kk<4;kk++){
        int kb = kk*32 + (lane>>4)*8;
        bf16x8 A[4], Bf[4];
        #pragma unroll
        for(int i=0;i<4;i++){
            int r = m0 + i*16 + (lane&15);
            A[i] = *(const bf16x8*)(smv + r*256 + ((2*kb) ^ (swz3(r)<<4)));
        }
        #pragma unroll
        for(int j=0;j<4;j++){
            int o = n0 + j*16 + (lane&15);
            Bf[j] = *(const bf16x8*)(smw + o*256 + ((2*kb) ^ (swz3(o)<<4)));
        }
        #pragma unroll
        for(int i=0;i<4;i++)
            #pragma unroll
            for(int j=0;j<4;j++)
                acc[i][j] = __builtin_amdgcn_mfma_f32_16x16x32_bf16(A[i], Bf[j], acc[i][j], 0,0,0);
    }
    __syncthreads();     // smv/smw reads done; smem becomes smo
    {
        int rq = (lane>>4)*4, cc = lane&15;
        #pragma unroll
        for(int j=0;j<4;j++){
            int col = n0 + j*16 + cc;
            #pragma unroll
            for(int i=0;i<4;i++)
                #pragma unroll
                for(int rg=0;rg<4;rg++){
                    int row = m0 + i*16 + rq + rg;
                    smo[row*C_ + col] = acc[i][j][rg];
                }
        }
    }
    __syncthreads();

    // phase 3: conv2(c1) + bias + smo -> single store
    int yt = tileI >> 1;
    int x0 = (tileI & 1) << 7;
    int c0 = (t & 15)*8;
    int pg = t >> 4;               // 16 groups x 8 px = 128 px
    float wreg[9][8];
    #pragma unroll
    for(int k=0;k<9;k++){
        float4 a = *(const float4*)(w2 + k*C_ + c0);
        float4 bq = *(const float4*)(w2 + k*C_ + c0 + 4);
        wreg[k][0]=a.x; wreg[k][1]=a.y; wreg[k][2]=a.z; wreg[k][3]=a.w;
        wreg[k][4]=bq.x; wreg[k][5]=bq.y; wreg[k][6]=bq.z; wreg[k][7]=bq.w;
    }
    float bias[8];
    {
        float4 b0 = *(const float4*)(bp + c0);
        float4 b1 = *(const float4*)(bp + c0 + 4);
        bias[0]=b0.x; bias[1]=b0.y; bias[2]=b0.z; bias[3]=b0.w;
        bias[4]=b1.x; bias[5]=b1.y; bias[6]=b1.z; bias[7]=b1.w;
    }
    const ushort* cb = c1 + (long)b*NPIX*C_;
    float* ob = out + ((long)b*NPIX + (long)yt*W_)*C_;

    float colA[3][8], colB[3][8], colC[3][8];
    int xbase = x0 + pg*8;

    auto loadcol = [&](float (*col)[8], int xcol){
        #pragma unroll
        for(int ky=0;ky<3;ky++){
            int yy = yt + ky - 1;
            if(xcol>=0 && xcol<W_ && yy>=0 && yy<H_){
                uint4 vv = *(const uint4*)(cb + ((long)yy*W_ + xcol)*C_ + c0);
                const ushort* pv = (const ushort*)&vv;
                #pragma unroll
                for(int i=0;i<8;i++) col[ky][i] = bf2f(pv[i]);
            } else {
                #pragma unroll
                for(int i=0;i<8;i++) col[ky][i] = 0.f;
            }
        }
    };
    loadcol(colA, xbase-1);
    loadcol(colB, xbase);
    #pragma unroll
    for(int q=0;q<8;q++){
        int xx = xbase + q;
        int r  = pg*8 + q;          // local pixel index in tile
        loadcol(colC, xx+1);
        float s[8];
        #pragma unroll
        for(int i=0;i<8;i++){
            float a = 0.f;
            #pragma unroll
            for(int ky=0;ky<3;ky++){
                a += colA[ky][i]*wreg[ky*3+0][i];
                a += colB[ky][i]*wreg[ky*3+1][i];
                a += colC[ky][i]*wreg[ky*3+2][i];
            }
            s[i] = a;
        }
        float4 o0, o1;
        o0.x = smo[r*C_ + c0 + 0] + bias[0] + s[0];
        o0.y = smo[r*C_ + c0 + 1] + bias[1] + s[1];
        o0.z = smo[r*C_ + c0 + 2] + bias[2] + s[2];
        o0.w = smo[r*C_ + c0 + 3] + bias[3] + s[3];
        o1.x = smo[r*C_ + c0 + 4] + bias[4] + s[4];
        o1.y = smo[r*C_ + c0 + 5] + bias[5] + s[5];
        o1.z = smo[r*C_ + c0 + 6] + bias[6] + s[6];
        o1.w = smo[r*C_ + c0 + 7] + bias[7] + s[7];
        float* op2 = ob + (long)xx*C_ + c0;
        *(float4*)(op2)     = o0;
        *(float4*)(op2 + 4) = o1;
        #pragma unroll
        for(int ky=0;ky<3;ky++)
            #pragma unroll
            for(int i=0;i<8;i++){ colA[ky][i]=colB[ky][i]; colB[ky][i]=colC[ky][i]; }
    }
}

extern "C" void kernel_launch(void* const* d_in, const int* in_sizes, int n_in,
                              void* d_out, int out_size, void* d_ws, size_t ws_size,
                              hipStream_t stream){
    (void)in_sizes; (void)n_in; (void)out_size; (void)ws_size;
    const float* x    = (const float*)d_in[0];
    const float* ilf  = (const float*)d_in[1];
    const float* Wq   = (const float*)d_in[2];
    const float* Wk   = (const float*)d_in[3];
    const float* Wv   = (const float*)d_in[4];
    const float* rsc  = (const float*)d_in[5];
    const float* Wp   = (const float*)d_in[6];
    const float* bp   = (const float*)d_in[7];
    const float* w1   = (const float*)d_in[8];
    const float* w2   = (const float*)d_in[9];
    float* out = (float*)d_out;
    char* ws = (char*)d_ws;

    ushort* vinp  = (ushort*)ws;                       // 64 MiB
    ushort* c1    = (ushort*)(ws + 67108864);          // 64 MiB (written by k4a)
    float*  TQ    = (float*)(ws + 67108864);           // 256 KiB, aliases c1 (dead until k4a)
    float*  S     = (float*)(ws + 134217728);          // 256 KiB  [zeroed]
    float*  nrm   = (float*)(ws + 134479872);          // 4 KiB    [zeroed]
    ushort* WeffT = (ushort*)(ws + 134483968);         // 128 KiB

    hipMemsetAsync(S, 0, 262144 + 4096, stream);
    hipLaunchKernelGGL(k12,      dim3(512),  dim3(512), 0, stream, x, Wv, S, vinp);
    hipLaunchKernelGGL(k3a,      dim3(512),  dim3(256), 0, stream, S, Wq, Wk, TQ, nrm);
    hipLaunchKernelGGL(k3b,      dim3(16),   dim3(256), 0, stream, TQ, Wk, rsc, Wp, nrm, WeffT);
    hipLaunchKernelGGL(k4a_conv1,dim3(2048), dim3(256), 0, stream, vinp, w1, c1);
    hipLaunchKernelGGL(k4bc,     dim3(2048), dim3(256), 0, stream, vinp, ilf, WeffT, bp, c1, w2, out);
}